// Round 1
// baseline (190.909 us; speedup 1.0000x reference)
//
#include <hip/hip_runtime.h>
#include <math.h>

// ---------------------------------------------------------------------------
// RootCauseAttention: per-node scores -> edge segment-sum -> global softmax
//   s_src = h @ W_edge[:H];  s_dst = h @ W_edge[H:];  s_node = h @ W_node
//   acc[d] = s_node[d] + b_node + sum_{e: dst=d} (s_src[src_e] + s_dst[d] + b_edge)
//   out = softmax(acc)
// Workspace layout (floats): s_src[N] | t_dst[N] | acc[N] | gmax | gsum
// ---------------------------------------------------------------------------

__device__ __forceinline__ void atomicMaxFloat(float* addr, float val) {
    // Works for mixed signs given init to -inf:
    //  non-negative floats: int compare == float compare
    //  negative floats: uint compare is reversed -> use atomicMin on uint
    if (val >= 0.0f) atomicMax((int*)addr, __float_as_int(val));
    else             atomicMin((unsigned int*)addr, __float_as_uint(val));
}

// One wave (64 lanes) per node. H/2 float2 per row (H=128 -> 1 per lane).
__global__ __launch_bounds__(256) void node_scores_kernel(
    const float* __restrict__ h,
    const float* __restrict__ W_edge,   // [2H]
    const float* __restrict__ b_edge,   // [1]
    const float* __restrict__ W_node,   // [H]
    const float* __restrict__ b_node,   // [1]
    float* __restrict__ s_src,
    float* __restrict__ t_dst,          // s_dst + b_edge
    float* __restrict__ acc,            // init to self score
    float* __restrict__ gmax,
    float* __restrict__ gsum,
    int N, int H)
{
    if (blockIdx.x == 0 && threadIdx.x == 0) { *gmax = -INFINITY; *gsum = 0.0f; }

    const int wave = threadIdx.x >> 6;
    const int lane = threadIdx.x & 63;
    const int wavesPerBlock = blockDim.x >> 6;
    const int n = blockIdx.x * wavesPerBlock + wave;
    if (n >= N) return;

    const float2* __restrict__ h2  = (const float2*)(h + (size_t)n * H);
    const float2* __restrict__ ws2 = (const float2*)(W_edge);
    const float2* __restrict__ wd2 = (const float2*)(W_edge + H);
    const float2* __restrict__ wn2 = (const float2*)(W_node);
    const int H2 = H >> 1;

    float ps = 0.0f, pd = 0.0f, pn = 0.0f;
    for (int i = lane; i < H2; i += 64) {
        float2 hv = h2[i];
        float2 a = ws2[i], b = wd2[i], c = wn2[i];
        ps = fmaf(hv.x, a.x, fmaf(hv.y, a.y, ps));
        pd = fmaf(hv.x, b.x, fmaf(hv.y, b.y, pd));
        pn = fmaf(hv.x, c.x, fmaf(hv.y, c.y, pn));
    }
    #pragma unroll
    for (int off = 32; off > 0; off >>= 1) {
        ps += __shfl_xor(ps, off, 64);
        pd += __shfl_xor(pd, off, 64);
        pn += __shfl_xor(pn, off, 64);
    }
    if (lane == 0) {
        s_src[n] = ps;
        t_dst[n] = pd + b_edge[0];
        acc[n]   = pn + b_node[0];
    }
}

// One thread per edge: acc[dst] += s_src[src] + t_dst[dst]
__global__ __launch_bounds__(256) void edge_accum_kernel(
    const int* __restrict__ ei,          // [2*E]: src row then dst row
    const float* __restrict__ s_src,
    const float* __restrict__ t_dst,
    float* __restrict__ acc,
    int E)
{
    int e = blockIdx.x * blockDim.x + threadIdx.x;
    if (e >= E) return;
    int s = ei[e];
    int d = ei[E + e];
    atomicAdd(&acc[d], s_src[s] + t_dst[d]);
}

__global__ __launch_bounds__(256) void reduce_max_kernel(
    const float* __restrict__ acc, float* __restrict__ gmax, int N)
{
    float m = -INFINITY;
    for (int i = blockIdx.x * blockDim.x + threadIdx.x; i < N;
         i += gridDim.x * blockDim.x)
        m = fmaxf(m, acc[i]);
    #pragma unroll
    for (int off = 32; off > 0; off >>= 1)
        m = fmaxf(m, __shfl_xor(m, off, 64));
    __shared__ float smax[4];
    int wave = threadIdx.x >> 6, lane = threadIdx.x & 63;
    if (lane == 0) smax[wave] = m;
    __syncthreads();
    if (threadIdx.x == 0) {
        float bm = smax[0];
        for (int w = 1; w < (int)(blockDim.x >> 6); ++w) bm = fmaxf(bm, smax[w]);
        atomicMaxFloat(gmax, bm);
    }
}

// out[i] = exp(acc[i]-max); partial sums -> gsum
__global__ __launch_bounds__(256) void exp_sum_kernel(
    const float* __restrict__ acc, const float* __restrict__ gmax,
    float* __restrict__ out, float* __restrict__ gsum, int N)
{
    const float mx = *gmax;
    float s = 0.0f;
    for (int i = blockIdx.x * blockDim.x + threadIdx.x; i < N;
         i += gridDim.x * blockDim.x) {
        float v = __expf(acc[i] - mx);
        out[i] = v;
        s += v;
    }
    #pragma unroll
    for (int off = 32; off > 0; off >>= 1)
        s += __shfl_xor(s, off, 64);
    __shared__ float ssum[4];
    int wave = threadIdx.x >> 6, lane = threadIdx.x & 63;
    if (lane == 0) ssum[wave] = s;
    __syncthreads();
    if (threadIdx.x == 0) {
        float bs = 0.0f;
        for (int w = 0; w < (int)(blockDim.x >> 6); ++w) bs += ssum[w];
        atomicAdd(gsum, bs);
    }
}

__global__ __launch_bounds__(256) void normalize_kernel(
    float* __restrict__ out, const float* __restrict__ gsum, int N)
{
    int i = blockIdx.x * blockDim.x + threadIdx.x;
    if (i >= N) return;
    out[i] *= (1.0f / *gsum);
}

extern "C" void kernel_launch(void* const* d_in, const int* in_sizes, int n_in,
                              void* d_out, int out_size, void* d_ws, size_t ws_size,
                              hipStream_t stream) {
    const float* h      = (const float*)d_in[0];
    const int*   ei     = (const int*)  d_in[1];
    const float* W_edge = (const float*)d_in[2];
    const float* b_edge = (const float*)d_in[3];
    const float* W_node = (const float*)d_in[4];
    const float* b_node = (const float*)d_in[5];

    const int H = in_sizes[2] / 2;            // W_edge has 2H elements
    const int N = in_sizes[0] / H;
    const int E = in_sizes[1] / 2;

    float* out   = (float*)d_out;
    float* ws    = (float*)d_ws;
    float* s_src = ws;
    float* t_dst = ws + N;
    float* acc   = ws + 2 * (size_t)N;
    float* gmax  = ws + 3 * (size_t)N;
    float* gsum  = ws + 3 * (size_t)N + 1;

    // 1) per-node scores (wave per node, 4 waves/block)
    {
        int wavesPerBlock = 4;
        int grid = (N + wavesPerBlock - 1) / wavesPerBlock;
        node_scores_kernel<<<grid, 256, 0, stream>>>(
            h, W_edge, b_edge, W_node, b_node,
            s_src, t_dst, acc, gmax, gsum, N, H);
    }
    // 2) edge accumulation
    {
        int grid = (E + 255) / 256;
        edge_accum_kernel<<<grid, 256, 0, stream>>>(ei, s_src, t_dst, acc, E);
    }
    // 3) softmax: max -> exp+sum -> normalize
    {
        int grid = (N + 255) / 256;
        reduce_max_kernel<<<grid, 256, 0, stream>>>(acc, gmax, N);
        exp_sum_kernel<<<grid, 256, 0, stream>>>(acc, gmax, out, gsum, N);
        normalize_kernel<<<grid, 256, 0, stream>>>(out, gsum, N);
    }
}

// Round 2
// 179.355 us; speedup vs baseline: 1.0644x; 1.0644x over previous
//
#include <hip/hip_runtime.h>
#include <math.h>

// ---------------------------------------------------------------------------
// RootCauseAttention: per-node scores -> edge segment-sum -> global softmax
//
// Key optimization vs round 1: device-scope fp32 atomicAdd (1.6M of them)
// executed at the memory-side coherent point (~17 G/s, WRITE_SIZE showed
// 32 B/atomic punch-through). Replace with per-XCD accumulator copies +
// WORKGROUP-scope atomics, which RMW in the XCD-local L2. Copy selected by
// the hardware XCC_ID register, so same-copy => same-L2 => atomicity holds.
//
// Workspace layout (floats):
//   s_src[N] | t_dst[N] | self[N] | acc[N] | gmax | gsum | copies[8*N]
// Fallback if ws too small: agent-scope atomics directly into acc (round-1).
// ---------------------------------------------------------------------------

#define NCOPIES 8

__device__ __forceinline__ int xcc_id() {
    int x;
    asm("s_getreg_b32 %0, hwreg(HW_REG_XCC_ID)" : "=s"(x));
    return x & (NCOPIES - 1);
}

__device__ __forceinline__ void atomicMaxFloat(float* addr, float val) {
    if (val >= 0.0f) atomicMax((int*)addr, __float_as_int(val));
    else             atomicMin((unsigned int*)addr, __float_as_uint(val));
}

// 16 lanes per node; float4 row loads (H=128 -> 2 float4 per lane).
// Also zeroes the per-XCD copies and inits gmax/gsum.
__global__ __launch_bounds__(256) void node_scores_kernel(
    const float* __restrict__ h,
    const float* __restrict__ W_edge,   // [2H]
    const float* __restrict__ b_edge,   // [1]
    const float* __restrict__ W_node,   // [H]
    const float* __restrict__ b_node,   // [1]
    float* __restrict__ s_src,
    float* __restrict__ t_dst,          // s_dst + b_edge
    float* __restrict__ self_sc,        // s_node + b_node
    float* __restrict__ acc,            // pre-init to self (fallback path)
    float* __restrict__ copies,         // [NCOPIES*N] zeroed here
    float* __restrict__ gmax,
    float* __restrict__ gsum,
    int N, int H, int use_copies)
{
    if (use_copies) {
        size_t total = (size_t)NCOPIES * N;
        size_t stride = (size_t)gridDim.x * blockDim.x;
        for (size_t i = (size_t)blockIdx.x * blockDim.x + threadIdx.x; i < total; i += stride)
            copies[i] = 0.0f;
    }
    if (blockIdx.x == 0 && threadIdx.x == 0) { *gmax = -INFINITY; *gsum = 0.0f; }

    const int lane16 = threadIdx.x & 15;
    const int n = (blockIdx.x * blockDim.x + threadIdx.x) >> 4;
    if (n >= N) return;

    const float4* __restrict__ h4  = (const float4*)(h + (size_t)n * H);
    const float4* __restrict__ ws4 = (const float4*)(W_edge);
    const float4* __restrict__ wd4 = (const float4*)(W_edge + H);
    const float4* __restrict__ wn4 = (const float4*)(W_node);
    const int H4 = H >> 2;

    float ps = 0.0f, pd = 0.0f, pn = 0.0f;
    for (int i = lane16; i < H4; i += 16) {
        float4 hv = h4[i];
        float4 a = ws4[i], b = wd4[i], c = wn4[i];
        ps = fmaf(hv.x, a.x, fmaf(hv.y, a.y, fmaf(hv.z, a.z, fmaf(hv.w, a.w, ps))));
        pd = fmaf(hv.x, b.x, fmaf(hv.y, b.y, fmaf(hv.z, b.z, fmaf(hv.w, b.w, pd))));
        pn = fmaf(hv.x, c.x, fmaf(hv.y, c.y, fmaf(hv.z, c.z, fmaf(hv.w, c.w, pn))));
    }
    // reduce within each 16-lane group (xor offsets < 16 stay in-group)
    #pragma unroll
    for (int off = 8; off > 0; off >>= 1) {
        ps += __shfl_xor(ps, off, 64);
        pd += __shfl_xor(pd, off, 64);
        pn += __shfl_xor(pn, off, 64);
    }
    if (lane16 == 0) {
        float self = pn + b_node[0];
        s_src[n]   = ps;
        t_dst[n]   = pd + b_edge[0];
        self_sc[n] = self;
        acc[n]     = self;   // only consumed in fallback path
    }
}

// 4 edges per thread; workgroup-scope atomics into the XCD-local copy.
__global__ __launch_bounds__(256) void edge_accum_copies_kernel(
    const int* __restrict__ ei,          // [2*E]: src row then dst row
    const float* __restrict__ s_src,
    const float* __restrict__ t_dst,
    float* __restrict__ copies,          // [NCOPIES*N]
    int N, int E, int vec_ok)
{
    float* __restrict__ mycopy = copies + (size_t)xcc_id() * N;
    const int base = (blockIdx.x * blockDim.x + threadIdx.x) * 4;
    if (base >= E) return;

    if (vec_ok && base + 4 <= E) {
        int4 s4 = *(const int4*)(ei + base);
        int4 d4 = *(const int4*)(ei + E + base);
        float v0 = s_src[s4.x] + t_dst[d4.x];
        float v1 = s_src[s4.y] + t_dst[d4.y];
        float v2 = s_src[s4.z] + t_dst[d4.z];
        float v3 = s_src[s4.w] + t_dst[d4.w];
        __hip_atomic_fetch_add(&mycopy[d4.x], v0, __ATOMIC_RELAXED, __HIP_MEMORY_SCOPE_WORKGROUP);
        __hip_atomic_fetch_add(&mycopy[d4.y], v1, __ATOMIC_RELAXED, __HIP_MEMORY_SCOPE_WORKGROUP);
        __hip_atomic_fetch_add(&mycopy[d4.z], v2, __ATOMIC_RELAXED, __HIP_MEMORY_SCOPE_WORKGROUP);
        __hip_atomic_fetch_add(&mycopy[d4.w], v3, __ATOMIC_RELAXED, __HIP_MEMORY_SCOPE_WORKGROUP);
    } else {
        for (int e = base; e < E && e < base + 4; ++e) {
            int s = ei[e], d = ei[E + e];
            __hip_atomic_fetch_add(&mycopy[d], s_src[s] + t_dst[d],
                                   __ATOMIC_RELAXED, __HIP_MEMORY_SCOPE_WORKGROUP);
        }
    }
}

// Fallback: agent-scope atomics straight into acc (pre-initialized to self).
__global__ __launch_bounds__(256) void edge_accum_fallback_kernel(
    const int* __restrict__ ei,
    const float* __restrict__ s_src,
    const float* __restrict__ t_dst,
    float* __restrict__ acc,
    int E)
{
    int e = blockIdx.x * blockDim.x + threadIdx.x;
    if (e >= E) return;
    int s = ei[e];
    int d = ei[E + e];
    atomicAdd(&acc[d], s_src[s] + t_dst[d]);
}

// acc[n] = self[n] + sum over copies (if use_copies); also global max.
__global__ __launch_bounds__(256) void combine_max_kernel(
    const float* __restrict__ self_sc,
    const float* __restrict__ copies,
    float* __restrict__ acc,
    float* __restrict__ gmax,
    int N, int use_copies)
{
    float m = -INFINITY;
    for (int i = blockIdx.x * blockDim.x + threadIdx.x; i < N;
         i += gridDim.x * blockDim.x) {
        float v;
        if (use_copies) {
            v = self_sc[i];
            #pragma unroll
            for (int x = 0; x < NCOPIES; ++x) v += copies[(size_t)x * N + i];
            acc[i] = v;
        } else {
            v = acc[i];
        }
        m = fmaxf(m, v);
    }
    #pragma unroll
    for (int off = 32; off > 0; off >>= 1)
        m = fmaxf(m, __shfl_xor(m, off, 64));
    __shared__ float smax[4];
    int wave = threadIdx.x >> 6, lane = threadIdx.x & 63;
    if (lane == 0) smax[wave] = m;
    __syncthreads();
    if (threadIdx.x == 0) {
        float bm = smax[0];
        for (int w = 1; w < (int)(blockDim.x >> 6); ++w) bm = fmaxf(bm, smax[w]);
        atomicMaxFloat(gmax, bm);
    }
}

__global__ __launch_bounds__(256) void exp_sum_kernel(
    const float* __restrict__ acc, const float* __restrict__ gmax,
    float* __restrict__ out, float* __restrict__ gsum, int N)
{
    const float mx = *gmax;
    float s = 0.0f;
    for (int i = blockIdx.x * blockDim.x + threadIdx.x; i < N;
         i += gridDim.x * blockDim.x) {
        float v = __expf(acc[i] - mx);
        out[i] = v;
        s += v;
    }
    #pragma unroll
    for (int off = 32; off > 0; off >>= 1)
        s += __shfl_xor(s, off, 64);
    __shared__ float ssum[4];
    int wave = threadIdx.x >> 6, lane = threadIdx.x & 63;
    if (lane == 0) ssum[wave] = s;
    __syncthreads();
    if (threadIdx.x == 0) {
        float bs = 0.0f;
        for (int w = 0; w < (int)(blockDim.x >> 6); ++w) bs += ssum[w];
        atomicAdd(gsum, bs);
    }
}

__global__ __launch_bounds__(256) void normalize_kernel(
    float* __restrict__ out, const float* __restrict__ gsum, int N)
{
    int i = blockIdx.x * blockDim.x + threadIdx.x;
    if (i >= N) return;
    out[i] *= (1.0f / *gsum);
}

extern "C" void kernel_launch(void* const* d_in, const int* in_sizes, int n_in,
                              void* d_out, int out_size, void* d_ws, size_t ws_size,
                              hipStream_t stream) {
    const float* h      = (const float*)d_in[0];
    const int*   ei     = (const int*)  d_in[1];
    const float* W_edge = (const float*)d_in[2];
    const float* b_edge = (const float*)d_in[3];
    const float* W_node = (const float*)d_in[4];
    const float* b_node = (const float*)d_in[5];

    const int H = in_sizes[2] / 2;            // W_edge has 2H elements
    const int N = in_sizes[0] / H;
    const int E = in_sizes[1] / 2;

    float* out    = (float*)d_out;
    float* ws     = (float*)d_ws;
    float* s_src  = ws;
    float* t_dst  = ws + (size_t)N;
    float* self_s = ws + 2 * (size_t)N;
    float* acc    = ws + 3 * (size_t)N;
    float* gmax   = ws + 4 * (size_t)N;
    float* gsum   = ws + 4 * (size_t)N + 1;
    float* copies = ws + 4 * (size_t)N + 2;

    const size_t need = (4 * (size_t)N + 2 + (size_t)NCOPIES * N) * sizeof(float);
    const int use_copies = (ws_size >= need) ? 1 : 0;

    // 1) node scores (16 lanes/node) + zero copies + init scalars
    {
        int threads = N * 16;
        int grid = (threads + 255) / 256;
        node_scores_kernel<<<grid, 256, 0, stream>>>(
            h, W_edge, b_edge, W_node, b_node,
            s_src, t_dst, self_s, acc, copies, gmax, gsum, N, H, use_copies);
    }
    // 2) edge accumulation
    if (use_copies) {
        int vec_ok = ((E & 3) == 0) ? 1 : 0;
        int grid = ((E + 3) / 4 + 255) / 256;
        edge_accum_copies_kernel<<<grid, 256, 0, stream>>>(
            ei, s_src, t_dst, copies, N, E, vec_ok);
    } else {
        int grid = (E + 255) / 256;
        edge_accum_fallback_kernel<<<grid, 256, 0, stream>>>(ei, s_src, t_dst, acc, E);
    }
    // 3) combine copies + self, global max
    combine_max_kernel<<<256, 256, 0, stream>>>(self_s, copies, acc, gmax, N, use_copies);
    // 4) exp + partial sums
    {
        int grid = (N + 255) / 256;
        exp_sum_kernel<<<grid, 256, 0, stream>>>(acc, gmax, out, gsum, N);
    }
    // 5) normalize
    {
        int grid = (N + 255) / 256;
        normalize_kernel<<<grid, 256, 0, stream>>>(out, gsum, N);
    }
}

// Round 3
// 119.396 us; speedup vs baseline: 1.5990x; 1.5022x over previous
//
#include <hip/hip_runtime.h>
#include <math.h>

// ---------------------------------------------------------------------------
// RootCauseAttention: per-node scores -> edge segment-sum -> global softmax
//
// Round-3 structure: the segment-sum is done with LDS histograms, NOT global
// atomics. Rounds 1-2 showed every global fp32 atomic executes memory-side
// (~32 B WRITE_SIZE each, ~18 G/s total) regardless of scope qualifier.
// Node space is split into R ranges of 16384 (64 KB LDS); grid is
// (B chunks) x (R ranges); each block scans its edge chunk, LDS-atomicAdds
// in-range dsts, then writes its histogram slice to partials[b] with plain
// stores. Combine kernel sums the B partials (+self) and feeds the softmax.
//
// Workspace (floats): s_src[N] | t_dst[N] | self[N] | acc[N] | gmax | gsum
//                     | partials[B*N]
// ---------------------------------------------------------------------------

#define RANGE_BITS 14
#define RANGE_SIZE (1 << RANGE_BITS)   // 16384 nodes/range, 64 KB LDS

__device__ __forceinline__ void atomicMaxFloat(float* addr, float val) {
    if (val >= 0.0f) atomicMax((int*)addr, __float_as_int(val));
    else             atomicMin((unsigned int*)addr, __float_as_uint(val));
}

// 16 lanes per node; float4 row loads (H=128 -> 2 float4 per lane).
__global__ __launch_bounds__(256) void node_scores_kernel(
    const float* __restrict__ h,
    const float* __restrict__ W_edge,   // [2H]
    const float* __restrict__ b_edge,   // [1]
    const float* __restrict__ W_node,   // [H]
    const float* __restrict__ b_node,   // [1]
    float* __restrict__ s_src,
    float* __restrict__ t_dst,          // s_dst + b_edge
    float* __restrict__ self_sc,        // s_node + b_node
    float* __restrict__ acc,            // pre-init to self (fallback path)
    float* __restrict__ gmax,
    float* __restrict__ gsum,
    int N, int H)
{
    if (blockIdx.x == 0 && threadIdx.x == 0) { *gmax = -INFINITY; *gsum = 0.0f; }

    const int lane16 = threadIdx.x & 15;
    const int n = (blockIdx.x * blockDim.x + threadIdx.x) >> 4;
    if (n >= N) return;

    const float4* __restrict__ h4  = (const float4*)(h + (size_t)n * H);
    const float4* __restrict__ ws4 = (const float4*)(W_edge);
    const float4* __restrict__ wd4 = (const float4*)(W_edge + H);
    const float4* __restrict__ wn4 = (const float4*)(W_node);
    const int H4 = H >> 2;

    float ps = 0.0f, pd = 0.0f, pn = 0.0f;
    for (int i = lane16; i < H4; i += 16) {
        float4 hv = h4[i];
        float4 a = ws4[i], b = wd4[i], c = wn4[i];
        ps = fmaf(hv.x, a.x, fmaf(hv.y, a.y, fmaf(hv.z, a.z, fmaf(hv.w, a.w, ps))));
        pd = fmaf(hv.x, b.x, fmaf(hv.y, b.y, fmaf(hv.z, b.z, fmaf(hv.w, b.w, pd))));
        pn = fmaf(hv.x, c.x, fmaf(hv.y, c.y, fmaf(hv.z, c.z, fmaf(hv.w, c.w, pn))));
    }
    #pragma unroll
    for (int off = 8; off > 0; off >>= 1) {
        ps += __shfl_xor(ps, off, 64);
        pd += __shfl_xor(pd, off, 64);
        pn += __shfl_xor(pn, off, 64);
    }
    if (lane16 == 0) {
        float self = pn + b_node[0];
        s_src[n]   = ps;
        t_dst[n]   = pd + b_edge[0];
        self_sc[n] = self;
        acc[n]     = self;   // consumed only in fallback path
    }
}

// Block (b,r): LDS histogram of node range r over edge chunk b.
__global__ __launch_bounds__(512) void edge_bin_kernel(
    const int* __restrict__ ei,          // [2*E]: src row then dst row
    const float* __restrict__ s_src,
    const float* __restrict__ t_dst,
    float* __restrict__ partials,        // [B*N]
    int N, int E, int chunk, int vec_ok)
{
    __shared__ float hist[RANGE_SIZE];
    const int b  = blockIdx.x;
    const int r  = blockIdx.y;
    const int lo = r << RANGE_BITS;
    const int hi = min(lo + RANGE_SIZE, N);

    for (int i = threadIdx.x; i < RANGE_SIZE; i += blockDim.x) hist[i] = 0.0f;
    __syncthreads();

    const int e0 = b * chunk;
    const int e1 = min(e0 + chunk, E);
    if (e0 < e1) {
        if (vec_ok) {
            const int nvec = (e1 - e0) >> 2;
            const int4* __restrict__ src4 = (const int4*)(ei + e0);
            const int4* __restrict__ dst4 = (const int4*)(ei + E + e0);
            for (int i = threadIdx.x; i < nvec; i += blockDim.x) {
                int4 d = dst4[i];
                int4 s = src4[i];
                if (d.x >= lo && d.x < hi) atomicAdd(&hist[d.x - lo], s_src[s.x] + t_dst[d.x]);
                if (d.y >= lo && d.y < hi) atomicAdd(&hist[d.y - lo], s_src[s.y] + t_dst[d.y]);
                if (d.z >= lo && d.z < hi) atomicAdd(&hist[d.z - lo], s_src[s.z] + t_dst[d.z]);
                if (d.w >= lo && d.w < hi) atomicAdd(&hist[d.w - lo], s_src[s.w] + t_dst[d.w]);
            }
            for (int e = e0 + 4 * nvec + threadIdx.x; e < e1; e += blockDim.x) {
                int d = ei[E + e];
                if (d >= lo && d < hi) atomicAdd(&hist[d - lo], s_src[ei[e]] + t_dst[d]);
            }
        } else {
            for (int e = e0 + threadIdx.x; e < e1; e += blockDim.x) {
                int d = ei[E + e];
                if (d >= lo && d < hi) atomicAdd(&hist[d - lo], s_src[ei[e]] + t_dst[d]);
            }
        }
    }
    __syncthreads();

    float* __restrict__ outp = partials + (size_t)b * N + lo;
    const int len = hi - lo;
    for (int i = threadIdx.x; i < len; i += blockDim.x) outp[i] = hist[i];
}

// Fallback: agent-scope atomics straight into acc (pre-initialized to self).
__global__ __launch_bounds__(256) void edge_accum_fallback_kernel(
    const int* __restrict__ ei,
    const float* __restrict__ s_src,
    const float* __restrict__ t_dst,
    float* __restrict__ acc,
    int E)
{
    int e = blockIdx.x * blockDim.x + threadIdx.x;
    if (e >= E) return;
    int s = ei[e];
    int d = ei[E + e];
    atomicAdd(&acc[d], s_src[s] + t_dst[d]);
}

// acc[n] = self[n] + sum_b partials[b][n] (if use_partials); also global max.
__global__ __launch_bounds__(256) void combine_max_kernel(
    const float* __restrict__ self_sc,
    const float* __restrict__ partials,
    float* __restrict__ acc,
    float* __restrict__ gmax,
    int N, int B, int use_partials)
{
    float m = -INFINITY;
    for (int i = blockIdx.x * blockDim.x + threadIdx.x; i < N;
         i += gridDim.x * blockDim.x) {
        float v;
        if (use_partials) {
            float v0 = self_sc[i], v1 = 0.0f, v2 = 0.0f, v3 = 0.0f;
            int b = 0;
            for (; b + 4 <= B; b += 4) {
                v0 += partials[(size_t)(b + 0) * N + i];
                v1 += partials[(size_t)(b + 1) * N + i];
                v2 += partials[(size_t)(b + 2) * N + i];
                v3 += partials[(size_t)(b + 3) * N + i];
            }
            for (; b < B; ++b) v0 += partials[(size_t)b * N + i];
            v = (v0 + v1) + (v2 + v3);
            acc[i] = v;
        } else {
            v = acc[i];
        }
        m = fmaxf(m, v);
    }
    #pragma unroll
    for (int off = 32; off > 0; off >>= 1)
        m = fmaxf(m, __shfl_xor(m, off, 64));
    __shared__ float smax[4];
    int wave = threadIdx.x >> 6, lane = threadIdx.x & 63;
    if (lane == 0) smax[wave] = m;
    __syncthreads();
    if (threadIdx.x == 0) {
        float bm = smax[0];
        for (int w = 1; w < (int)(blockDim.x >> 6); ++w) bm = fmaxf(bm, smax[w]);
        atomicMaxFloat(gmax, bm);
    }
}

__global__ __launch_bounds__(256) void exp_sum_kernel(
    const float* __restrict__ acc, const float* __restrict__ gmax,
    float* __restrict__ out, float* __restrict__ gsum, int N)
{
    const float mx = *gmax;
    float s = 0.0f;
    for (int i = blockIdx.x * blockDim.x + threadIdx.x; i < N;
         i += gridDim.x * blockDim.x) {
        float v = __expf(acc[i] - mx);
        out[i] = v;
        s += v;
    }
    #pragma unroll
    for (int off = 32; off > 0; off >>= 1)
        s += __shfl_xor(s, off, 64);
    __shared__ float ssum[4];
    int wave = threadIdx.x >> 6, lane = threadIdx.x & 63;
    if (lane == 0) ssum[wave] = s;
    __syncthreads();
    if (threadIdx.x == 0) {
        float bs = 0.0f;
        for (int w = 0; w < (int)(blockDim.x >> 6); ++w) bs += ssum[w];
        atomicAdd(gsum, bs);
    }
}

__global__ __launch_bounds__(256) void normalize_kernel(
    float* __restrict__ out, const float* __restrict__ gsum, int N)
{
    int i = blockIdx.x * blockDim.x + threadIdx.x;
    if (i >= N) return;
    out[i] *= (1.0f / *gsum);
}

extern "C" void kernel_launch(void* const* d_in, const int* in_sizes, int n_in,
                              void* d_out, int out_size, void* d_ws, size_t ws_size,
                              hipStream_t stream) {
    const float* h      = (const float*)d_in[0];
    const int*   ei     = (const int*)  d_in[1];
    const float* W_edge = (const float*)d_in[2];
    const float* b_edge = (const float*)d_in[3];
    const float* W_node = (const float*)d_in[4];
    const float* b_node = (const float*)d_in[5];

    const int H = in_sizes[2] / 2;            // W_edge has 2H elements
    const int N = in_sizes[0] / H;
    const int E = in_sizes[1] / 2;

    float* out    = (float*)d_out;
    float* ws     = (float*)d_ws;
    float* s_src  = ws;
    float* t_dst  = ws + (size_t)N;
    float* self_s = ws + 2 * (size_t)N;
    float* acc    = ws + 3 * (size_t)N;
    float* gmax   = ws + 4 * (size_t)N;
    float* gsum   = ws + 4 * (size_t)N + 1;
    float* partials = ws + 4 * (size_t)N + 2;

    // How many partial copies fit in the workspace?
    const size_t base_floats = 4 * (size_t)N + 2;
    int B = 0;
    if (ws_size / sizeof(float) > base_floats) {
        size_t avail = ws_size / sizeof(float) - base_floats;
        B = (int)(avail / (size_t)N);
    }
    if (B > 64) B = 64;
    const int R = (N + RANGE_SIZE - 1) >> RANGE_BITS;
    const int use_partials = (B >= 16) ? 1 : 0;

    // 1) node scores (16 lanes/node) + init scalars
    {
        int threads = N * 16;
        int grid = (threads + 255) / 256;
        node_scores_kernel<<<grid, 256, 0, stream>>>(
            h, W_edge, b_edge, W_node, b_node,
            s_src, t_dst, self_s, acc, gmax, gsum, N, H);
    }
    // 2) edge accumulation
    if (use_partials) {
        int chunk = (((E + B - 1) / B) + 3) & ~3;   // 4-aligned chunk starts
        int vec_ok = ((E & 3) == 0) ? 1 : 0;        // dst row 16B-aligned
        dim3 grid(B, R);
        edge_bin_kernel<<<grid, 512, 0, stream>>>(
            ei, s_src, t_dst, partials, N, E, chunk, vec_ok);
    } else {
        int grid = (E + 255) / 256;
        edge_accum_fallback_kernel<<<grid, 256, 0, stream>>>(ei, s_src, t_dst, acc, E);
    }
    // 3) combine partials + self, global max
    combine_max_kernel<<<256, 256, 0, stream>>>(self_s, partials, acc, gmax, N, B, use_partials);
    // 4) exp + partial sums
    {
        int grid = (N + 255) / 256;
        exp_sum_kernel<<<grid, 256, 0, stream>>>(acc, gmax, out, gsum, N);
    }
    // 5) normalize
    {
        int grid = (N + 255) / 256;
        normalize_kernel<<<grid, 256, 0, stream>>>(out, gsum, N);
    }
}